// Round 1
// baseline (2759.674 us; speedup 1.0000x reference)
//
#include <hip/hip_runtime.h>
#include <math.h>

#define IN_DIM 512
#define DD 256
#define BM 128
#define BN 128
#define BK 16

// ---- ordered-float <-> uint mapping for atomicMax on floats ----
__device__ __forceinline__ unsigned f2o(float f) {
  unsigned b = __float_as_uint(f);
  return (b & 0x80000000u) ? ~b : (b | 0x80000000u);
}
__device__ __forceinline__ float o2f(unsigned u) {
  return __uint_as_float((u & 0x80000000u) ? (u ^ 0x80000000u) : ~u);
}

// ---- prep: w1 = W @ a_w[:D], w2 = W @ a_w[D:], c1 = bW.a1, c2 = bW.a2 ----
__global__ void prep_kernel(const float* __restrict__ W, const float* __restrict__ bW,
                            const float* __restrict__ a_w,
                            float* __restrict__ w1, float* __restrict__ w2,
                            float* __restrict__ c12) {
  int i = threadIdx.x;  // 0..255
  float s1 = 0.f, s2 = 0.f;
  for (int j = 0; j < DD; ++j) {
    float wv = W[i * DD + j];
    s1 += wv * a_w[j];
    s2 += wv * a_w[DD + j];
  }
  w1[i] = s1;
  w2[i] = s2;
  __shared__ float r1[256], r2[256];
  r1[i] = bW[i] * a_w[i];
  r2[i] = bW[i] * a_w[DD + i];
  __syncthreads();
  for (int s = 128; s > 0; s >>= 1) {
    if (i < s) { r1[i] += r1[i + s]; r2[i] += r2[i + s]; }
    __syncthreads();
  }
  if (i == 0) { c12[0] = r1[0]; c12[1] = r2[0]; }
}

// ---- mapping GEMM: Y = relu(X @ Wm + bm); optional fused row-dot s += Y.wvec ----
// X: [M, IN_DIM], Wm: [IN_DIM, DD], Y: [M, DD] (may be null), sout: [M] (atomic partials)
__global__ __launch_bounds__(256) void map_gemm(
    const float* __restrict__ X, const float* __restrict__ Wm,
    const float* __restrict__ bm, float* __restrict__ Y,
    const float* __restrict__ wvec, float* __restrict__ sout, int M) {
  __shared__ float As[BK][BM];
  __shared__ float Bs[BK][BN];
  const int t = threadIdx.x;
  const int col0 = blockIdx.x * BN;       // 0 or 128
  const int row0 = blockIdx.y * BM;
  const int tr = t >> 4;                  // 0..15 -> rows tr*8..tr*8+7
  const int tc = t & 15;                  // 0..15 -> cols tc*8..tc*8+7
  // A staging map: thread -> row t/2, k-offset (t&1)*8, 8 consecutive floats
  const int arow = t >> 1;
  const int akb = (t & 1) * 8;
  // B staging map: thread -> k row t/16, col (t&15)*8, 8 consecutive floats
  const int bk = t >> 4;
  const int bcol = (t & 15) * 8;

  float acc[8][8];
#pragma unroll
  for (int i = 0; i < 8; ++i)
#pragma unroll
    for (int j = 0; j < 8; ++j) acc[i][j] = 0.f;

  for (int k0 = 0; k0 < IN_DIM; k0 += BK) {
    int gr = row0 + arow;
    if (gr >= M) gr = M - 1;  // clamp; tail rows computed but never stored
    const float4* ap = reinterpret_cast<const float4*>(&X[(size_t)gr * IN_DIM + k0 + akb]);
    float4 a0 = ap[0];
    float4 a1 = ap[1];
    const float4* bp = reinterpret_cast<const float4*>(&Wm[(size_t)(k0 + bk) * DD + col0 + bcol]);
    float4 b0 = bp[0];
    float4 b1 = bp[1];

    __syncthreads();  // previous tile's compute done
    As[akb + 0][arow] = a0.x; As[akb + 1][arow] = a0.y;
    As[akb + 2][arow] = a0.z; As[akb + 3][arow] = a0.w;
    As[akb + 4][arow] = a1.x; As[akb + 5][arow] = a1.y;
    As[akb + 6][arow] = a1.z; As[akb + 7][arow] = a1.w;
    *reinterpret_cast<float4*>(&Bs[bk][bcol]) = b0;
    *reinterpret_cast<float4*>(&Bs[bk][bcol + 4]) = b1;
    __syncthreads();

#pragma unroll
    for (int k = 0; k < BK; ++k) {
      float4 t0 = *reinterpret_cast<const float4*>(&As[k][tr * 8]);
      float4 t1 = *reinterpret_cast<const float4*>(&As[k][tr * 8 + 4]);
      float4 u0 = *reinterpret_cast<const float4*>(&Bs[k][tc * 8]);
      float4 u1 = *reinterpret_cast<const float4*>(&Bs[k][tc * 8 + 4]);
      float a[8] = {t0.x, t0.y, t0.z, t0.w, t1.x, t1.y, t1.z, t1.w};
      float b[8] = {u0.x, u0.y, u0.z, u0.w, u1.x, u1.y, u1.z, u1.w};
#pragma unroll
      for (int i = 0; i < 8; ++i)
#pragma unroll
        for (int j = 0; j < 8; ++j) acc[i][j] = fmaf(a[i], b[j], acc[i][j]);
    }
  }

  // bias + relu
  float bv[8];
#pragma unroll
  for (int j = 0; j < 8; ++j) bv[j] = bm[col0 + tc * 8 + j];
#pragma unroll
  for (int i = 0; i < 8; ++i)
#pragma unroll
    for (int j = 0; j < 8; ++j) {
      float v = acc[i][j] + bv[j];
      acc[i][j] = v > 0.f ? v : 0.f;
    }

  if (Y != nullptr) {
#pragma unroll
    for (int i = 0; i < 8; ++i) {
      int r = row0 + tr * 8 + i;
      if (r < M) {
        float4 o0 = {acc[i][0], acc[i][1], acc[i][2], acc[i][3]};
        float4 o1 = {acc[i][4], acc[i][5], acc[i][6], acc[i][7]};
        float4* yp = reinterpret_cast<float4*>(&Y[(size_t)r * DD + col0 + tc * 8]);
        yp[0] = o0;
        yp[1] = o1;
      }
    }
  }

  if (sout != nullptr) {
    float wv[8];
#pragma unroll
    for (int j = 0; j < 8; ++j) wv[j] = wvec[col0 + tc * 8 + j];
#pragma unroll
    for (int i = 0; i < 8; ++i) {
      float p = 0.f;
#pragma unroll
      for (int j = 0; j < 8; ++j) p = fmaf(acc[i][j], wv[j], p);
      // reduce across the 16 tc-lanes sharing this row (consecutive lanes)
      for (int d = 8; d > 0; d >>= 1) p += __shfl_down(p, d, 16);
      if (tc == 0) {
        int r = row0 + tr * 8 + i;
        if (r < M) atomicAdd(&sout[r], p);
      }
    }
  }
}

// ---- edge pass 1: e = s_src[src] + s_dst[dst] + const; segment max ----
__global__ void edge_score_kernel(const int* __restrict__ src, const int* __restrict__ dst,
                                  const float* __restrict__ s_src, const float* __restrict__ s_dst,
                                  const float* __restrict__ c12, const float* __restrict__ a_b,
                                  float* __restrict__ e, unsigned* __restrict__ m_u, int E) {
  int i = blockIdx.x * blockDim.x + threadIdx.x;
  if (i >= E) return;
  float ev = s_src[src[i]] + s_dst[dst[i]] + c12[0] + c12[1] + a_b[0];
  e[i] = ev;
  atomicMax(&m_u[src[i]], f2o(ev));
}

// ---- edge pass 2: ex = exp(e - m[src]); denom accumulate ----
__global__ void edge_exp_kernel(const int* __restrict__ src, const unsigned* __restrict__ m_u,
                                float* __restrict__ e, float* __restrict__ denom, int E) {
  int i = blockIdx.x * blockDim.x + threadIdx.x;
  if (i >= E) return;
  int s = src[i];
  float ex = expf(e[i] - o2f(m_u[s]));
  e[i] = ex;
  atomicAdd(&denom[s], ex);
}

// ---- edge pass 3: agg[src] += alpha * ho[dst]; one wave per edge ----
__global__ void edge_scatter_kernel(const int* __restrict__ src, const int* __restrict__ dst,
                                    const float* __restrict__ e, const float* __restrict__ denom,
                                    const float* __restrict__ ho, float* __restrict__ agg, int E) {
  int wid = (blockIdx.x * blockDim.x + threadIdx.x) >> 6;
  int lane = threadIdx.x & 63;
  if (wid >= E) return;
  int s = src[wid], d = dst[wid];
  float alpha = e[wid] / denom[s];
  float4 v = *reinterpret_cast<const float4*>(&ho[(size_t)d * DD + lane * 4]);
  float* ap = &agg[(size_t)s * DD + lane * 4];
  atomicAdd(ap + 0, alpha * v.x);
  atomicAdd(ap + 1, alpha * v.y);
  atomicAdd(ap + 2, alpha * v.z);
  atomicAdd(ap + 3, alpha * v.w);
}

// ---- final: row-wise L2 normalize in place; one wave per row ----
__global__ void l2norm_kernel(float* __restrict__ Y, long R) {
  long wid = ((long)blockIdx.x * blockDim.x + threadIdx.x) >> 6;
  int lane = threadIdx.x & 63;
  if (wid >= R) return;
  float4* p = reinterpret_cast<float4*>(&Y[wid * DD + lane * 4]);
  float4 v = *p;
  float ss = v.x * v.x + v.y * v.y + v.z * v.z + v.w * v.w;
#pragma unroll
  for (int d = 32; d > 0; d >>= 1) ss += __shfl_xor(ss, d, 64);
  float inv = 1.0f / fmaxf(sqrtf(ss), 1e-12f);
  v.x *= inv; v.y *= inv; v.z *= inv; v.w *= inv;
  *p = v;
}

extern "C" void kernel_launch(void* const* d_in, const int* in_sizes, int n_in,
                              void* d_out, int out_size, void* d_ws, size_t ws_size,
                              hipStream_t stream) {
  const float* feat_prefix = (const float*)d_in[0];
  const float* feat_other  = (const float*)d_in[1];
  const int*   src         = (const int*)d_in[2];
  const int*   dst         = (const int*)d_in[3];
  const float* Wm_p        = (const float*)d_in[4];
  const float* bm_p        = (const float*)d_in[5];
  const float* Wm_o        = (const float*)d_in[6];
  const float* bm_o        = (const float*)d_in[7];
  const float* W           = (const float*)d_in[8];
  const float* bW          = (const float*)d_in[9];
  const float* a_w         = (const float*)d_in[10];
  const float* a_b         = (const float*)d_in[11];

  const int NP = in_sizes[0] / IN_DIM;
  const int NO = in_sizes[1] / IN_DIM;
  const int E  = in_sizes[2];

  float* out     = (float*)d_out;
  float* agg_out = out;                        // [NP, DD]
  float* ho_out  = out + (size_t)NP * DD;      // [NO, DD]

  float* ws    = (float*)d_ws;
  float* w1    = ws;                // 256
  float* w2    = ws + 256;          // 256
  float* c12   = ws + 512;          // 2
  float* s_src = ws + 1024;         // NP
  float* s_dst = s_src + NP;        // NO
  unsigned* m_u = (unsigned*)(s_dst + NO);   // NP (init 0 == ordered floor)
  float* denom  = (float*)(m_u + NP);        // NP
  float* e      = denom + NP;                // E

  // zero s_src, s_dst, m_u, denom (contiguous) and the agg output region
  hipMemsetAsync(s_src, 0, (size_t)(NP + NO + NP + NP) * sizeof(float), stream);
  hipMemsetAsync(agg_out, 0, (size_t)NP * DD * sizeof(float), stream);

  prep_kernel<<<1, 256, 0, stream>>>(W, bW, a_w, w1, w2, c12);

  {
    dim3 g(DD / BN, (NP + BM - 1) / BM);
    map_gemm<<<g, 256, 0, stream>>>(feat_prefix, Wm_p, bm_p, nullptr, w1, s_src, NP);
  }
  {
    dim3 g(DD / BN, (NO + BM - 1) / BM);
    map_gemm<<<g, 256, 0, stream>>>(feat_other, Wm_o, bm_o, ho_out, w2, s_dst, NO);
  }

  edge_score_kernel<<<(E + 255) / 256, 256, 0, stream>>>(src, dst, s_src, s_dst, c12, a_b, e, m_u, E);
  edge_exp_kernel<<<(E + 255) / 256, 256, 0, stream>>>(src, m_u, e, denom, E);
  edge_scatter_kernel<<<(E + 3) / 4, 256, 0, stream>>>(src, dst, e, denom, ho_out, agg_out, E);

  long R = (long)NP + NO;
  l2norm_kernel<<<(int)((R + 3) / 4), 256, 0, stream>>>(out, R);
}

// Round 2
// 1060.441 us; speedup vs baseline: 2.6024x; 2.6024x over previous
//
#include <hip/hip_runtime.h>
#include <math.h>

#define IN_DIM 512
#define DD 256
#define BM 128
#define BN 128
#define BK 16
#define NEG_INF -3.402823466e+38f

// ---- prep: w2 = W @ a_w[D:2D]  (softmax shift-invariance removes everything else) ----
__global__ void prep_w2(const float* __restrict__ W, const float* __restrict__ a_w,
                        float* __restrict__ w2) {
  int i = threadIdx.x;  // 0..255
  float s = 0.f;
  for (int j = 0; j < DD; ++j) s = fmaf(W[i * DD + j], a_w[DD + j], s);
  w2[i] = s;
}

// ---- mapping GEMM: Y = relu(X @ Wm + bm); fused row-dot s += Y.wvec ----
__global__ __launch_bounds__(256) void map_gemm(
    const float* __restrict__ X, const float* __restrict__ Wm,
    const float* __restrict__ bm, float* __restrict__ Y,
    const float* __restrict__ wvec, float* __restrict__ sout, int M) {
  __shared__ float As[BK][BM];
  __shared__ float Bs[BK][BN];
  const int t = threadIdx.x;
  const int col0 = blockIdx.x * BN;
  const int row0 = blockIdx.y * BM;
  const int tr = t >> 4;
  const int tc = t & 15;
  const int arow = t >> 1;
  const int akb = (t & 1) * 8;
  const int bk = t >> 4;
  const int bcol = (t & 15) * 8;

  float acc[8][8];
#pragma unroll
  for (int i = 0; i < 8; ++i)
#pragma unroll
    for (int j = 0; j < 8; ++j) acc[i][j] = 0.f;

  for (int k0 = 0; k0 < IN_DIM; k0 += BK) {
    int gr = row0 + arow;
    if (gr >= M) gr = M - 1;  // clamp; tail rows computed but never stored
    const float4* ap = reinterpret_cast<const float4*>(&X[(size_t)gr * IN_DIM + k0 + akb]);
    float4 a0 = ap[0];
    float4 a1 = ap[1];
    const float4* bp = reinterpret_cast<const float4*>(&Wm[(size_t)(k0 + bk) * DD + col0 + bcol]);
    float4 b0 = bp[0];
    float4 b1 = bp[1];

    __syncthreads();
    As[akb + 0][arow] = a0.x; As[akb + 1][arow] = a0.y;
    As[akb + 2][arow] = a0.z; As[akb + 3][arow] = a0.w;
    As[akb + 4][arow] = a1.x; As[akb + 5][arow] = a1.y;
    As[akb + 6][arow] = a1.z; As[akb + 7][arow] = a1.w;
    *reinterpret_cast<float4*>(&Bs[bk][bcol]) = b0;
    *reinterpret_cast<float4*>(&Bs[bk][bcol + 4]) = b1;
    __syncthreads();

#pragma unroll
    for (int k = 0; k < BK; ++k) {
      float4 t0 = *reinterpret_cast<const float4*>(&As[k][tr * 8]);
      float4 t1 = *reinterpret_cast<const float4*>(&As[k][tr * 8 + 4]);
      float4 u0 = *reinterpret_cast<const float4*>(&Bs[k][tc * 8]);
      float4 u1 = *reinterpret_cast<const float4*>(&Bs[k][tc * 8 + 4]);
      float a[8] = {t0.x, t0.y, t0.z, t0.w, t1.x, t1.y, t1.z, t1.w};
      float b[8] = {u0.x, u0.y, u0.z, u0.w, u1.x, u1.y, u1.z, u1.w};
#pragma unroll
      for (int i = 0; i < 8; ++i)
#pragma unroll
        for (int j = 0; j < 8; ++j) acc[i][j] = fmaf(a[i], b[j], acc[i][j]);
    }
  }

  float bv[8];
#pragma unroll
  for (int j = 0; j < 8; ++j) bv[j] = bm[col0 + tc * 8 + j];
#pragma unroll
  for (int i = 0; i < 8; ++i)
#pragma unroll
    for (int j = 0; j < 8; ++j) {
      float v = acc[i][j] + bv[j];
      acc[i][j] = v > 0.f ? v : 0.f;
    }

#pragma unroll
  for (int i = 0; i < 8; ++i) {
    int r = row0 + tr * 8 + i;
    if (r < M) {
      float4 o0 = {acc[i][0], acc[i][1], acc[i][2], acc[i][3]};
      float4 o1 = {acc[i][4], acc[i][5], acc[i][6], acc[i][7]};
      float4* yp = reinterpret_cast<float4*>(&Y[(size_t)r * DD + col0 + tc * 8]);
      yp[0] = o0;
      yp[1] = o1;
    }
  }

  float wv[8];
#pragma unroll
  for (int j = 0; j < 8; ++j) wv[j] = wvec[col0 + tc * 8 + j];
#pragma unroll
  for (int i = 0; i < 8; ++i) {
    float p = 0.f;
#pragma unroll
    for (int j = 0; j < 8; ++j) p = fmaf(acc[i][j], wv[j], p);
    for (int d = 8; d > 0; d >>= 1) p += __shfl_down(p, d, 16);
    if (tc == 0) {
      int r = row0 + tr * 8 + i;
      if (r < M) atomicAdd(&sout[r], p);
    }
  }
}

// ---- CSR build: histogram of src ----
__global__ void hist_kernel(const int* __restrict__ src, int* __restrict__ deg, int E) {
  int i = blockIdx.x * blockDim.x + threadIdx.x;
  if (i < E) atomicAdd(&deg[src[i]], 1);
}

// ---- single-block exclusive scan over deg -> rowptr, cursor ----
#define SCAN_T 1024
__global__ __launch_bounds__(SCAN_T) void scan_kernel(
    const int* __restrict__ deg, int* __restrict__ rowptr,
    int* __restrict__ cursor, int NP) {
  __shared__ int sums[SCAN_T];
  int t = threadIdx.x;
  int items = (NP + SCAN_T - 1) / SCAN_T;
  int beg = t * items;
  int end = beg + items; if (end > NP) end = NP; if (beg > NP) beg = NP;
  int local = 0;
  for (int i = beg; i < end; ++i) local += deg[i];
  sums[t] = local;
  __syncthreads();
  for (int off = 1; off < SCAN_T; off <<= 1) {
    int u = (t >= off) ? sums[t - off] : 0;
    __syncthreads();
    sums[t] += u;
    __syncthreads();
  }
  int run = sums[t] - local;  // exclusive prefix of this thread's chunk
  for (int i = beg; i < end; ++i) {
    rowptr[i] = run;
    cursor[i] = run;
    run += deg[i];
  }
  if (t == SCAN_T - 1) rowptr[NP] = run;
}

// ---- bucket fill: group dst by src segment ----
__global__ void fill_kernel(const int* __restrict__ src, const int* __restrict__ dst,
                            int* __restrict__ cursor, int* __restrict__ ebuf, int E) {
  int i = blockIdx.x * blockDim.x + threadIdx.x;
  if (i < E) {
    int pos = atomicAdd(&cursor[src[i]], 1);
    ebuf[pos] = dst[i];
  }
}

// ---- per-segment softmax + weighted gather + fused l2norm; one wave per node ----
__global__ void agg_kernel(const int* __restrict__ rowptr, const int* __restrict__ ebuf,
                           const float* __restrict__ s_dst, const float* __restrict__ ho,
                           float* __restrict__ agg, int NP) {
  int p = (int)(((long)blockIdx.x * blockDim.x + threadIdx.x) >> 6);
  int lane = threadIdx.x & 63;
  if (p >= NP) return;
  int beg = rowptr[p], end = rowptr[p + 1];
  float4 acc = {0.f, 0.f, 0.f, 0.f};
  if (beg < end) {
    // lane-parallel segment max
    float m = NEG_INF;
    for (int j0 = beg; j0 < end; j0 += 64) {
      int j = j0 + lane;
      float v = (j < end) ? s_dst[ebuf[j]] : NEG_INF;
      m = fmaxf(m, v);
    }
#pragma unroll
    for (int d = 32; d > 0; d >>= 1) m = fmaxf(m, __shfl_xor(m, d, 64));
    // lane-parallel denom
    float denom = 0.f;
    for (int j0 = beg; j0 < end; j0 += 64) {
      int j = j0 + lane;
      denom += (j < end) ? __expf(s_dst[ebuf[j]] - m) : 0.f;
    }
#pragma unroll
    for (int d = 32; d > 0; d >>= 1) denom += __shfl_xor(denom, d, 64);
    float inv_denom = 1.f / denom;
    // weighted gather: wave reads one 1KB ho row per edge
    for (int j = beg; j < end; ++j) {
      int dd = ebuf[j];
      float w = __expf(s_dst[dd] - m) * inv_denom;
      float4 v = *reinterpret_cast<const float4*>(&ho[(size_t)dd * DD + lane * 4]);
      acc.x = fmaf(w, v.x, acc.x);
      acc.y = fmaf(w, v.y, acc.y);
      acc.z = fmaf(w, v.z, acc.z);
      acc.w = fmaf(w, v.w, acc.w);
    }
  }
  // fused row l2norm
  float ss = acc.x * acc.x + acc.y * acc.y + acc.z * acc.z + acc.w * acc.w;
#pragma unroll
  for (int d = 32; d > 0; d >>= 1) ss += __shfl_xor(ss, d, 64);
  float inv = 1.0f / fmaxf(sqrtf(ss), 1e-12f);
  float4 o = {acc.x * inv, acc.y * inv, acc.z * inv, acc.w * inv};
  *reinterpret_cast<float4*>(&agg[(size_t)p * DD + lane * 4]) = o;
}

// ---- row-wise L2 normalize in place; one wave per row ----
__global__ void l2norm_kernel(float* __restrict__ Y, long R) {
  long wid = ((long)blockIdx.x * blockDim.x + threadIdx.x) >> 6;
  int lane = threadIdx.x & 63;
  if (wid >= R) return;
  float4* p = reinterpret_cast<float4*>(&Y[wid * DD + lane * 4]);
  float4 v = *p;
  float ss = v.x * v.x + v.y * v.y + v.z * v.z + v.w * v.w;
#pragma unroll
  for (int d = 32; d > 0; d >>= 1) ss += __shfl_xor(ss, d, 64);
  float inv = 1.0f / fmaxf(sqrtf(ss), 1e-12f);
  v.x *= inv; v.y *= inv; v.z *= inv; v.w *= inv;
  *p = v;
}

extern "C" void kernel_launch(void* const* d_in, const int* in_sizes, int n_in,
                              void* d_out, int out_size, void* d_ws, size_t ws_size,
                              hipStream_t stream) {
  const float* feat_other  = (const float*)d_in[1];
  const int*   src         = (const int*)d_in[2];
  const int*   dst         = (const int*)d_in[3];
  const float* Wm_o        = (const float*)d_in[6];
  const float* bm_o        = (const float*)d_in[7];
  const float* W           = (const float*)d_in[8];
  const float* a_w         = (const float*)d_in[10];

  const int NP = in_sizes[0] / IN_DIM;
  const int NO = in_sizes[1] / IN_DIM;
  const int E  = in_sizes[2];

  float* out     = (float*)d_out;
  float* agg_out = out;                        // [NP, DD]
  float* ho_out  = out + (size_t)NP * DD;      // [NO, DD]

  // workspace layout
  float* ws     = (float*)d_ws;
  float* s_dst  = ws;                          // NO floats (zeroed)
  int*   deg    = (int*)(ws + NO);             // NP ints  (zeroed)
  int*   rowptr = deg + NP;                    // NP+1
  int*   cursor = rowptr + NP + 1;             // NP
  int*   ebuf   = cursor + NP;                 // E
  float* w2     = (float*)(ebuf + E);          // 256

  // zero s_dst + deg (contiguous)
  hipMemsetAsync(s_dst, 0, (size_t)(NO + NP) * sizeof(float), stream);

  prep_w2<<<1, 256, 0, stream>>>(W, a_w, w2);

  {
    dim3 g(DD / BN, (NO + BM - 1) / BM);
    map_gemm<<<g, 256, 0, stream>>>(feat_other, Wm_o, bm_o, ho_out, w2, s_dst, NO);
  }

  hist_kernel<<<(E + 255) / 256, 256, 0, stream>>>(src, deg, E);
  scan_kernel<<<1, SCAN_T, 0, stream>>>(deg, rowptr, cursor, NP);
  fill_kernel<<<(E + 255) / 256, 256, 0, stream>>>(src, dst, cursor, ebuf, E);

  agg_kernel<<<(NP * 64 + 255) / 256, 256, 0, stream>>>(rowptr, ebuf, s_dst, ho_out, agg_out, NP);

  l2norm_kernel<<<(int)(((long)NO + 3) / 4), 256, 0, stream>>>(ho_out, (long)NO);
}

// Round 3
// 604.417 us; speedup vs baseline: 4.5658x; 1.7545x over previous
//
#include <hip/hip_runtime.h>
#include <math.h>

#define IN_DIM 512
#define DD 256
#define NEG_INF -3.402823466e+38f

typedef __attribute__((ext_vector_type(8))) short short8_t;
typedef __attribute__((ext_vector_type(4))) float f32x4_t;

// ---- RNE split: x ~= hi(bf16) + lo(bf16), err ~2^-18 rel ----
__device__ __forceinline__ void split1(float x, ushort& h, ushort& l) {
  unsigned u = __float_as_uint(x);
  unsigned hr = (u + 0x7FFFu + ((u >> 16) & 1u)) >> 16;
  h = (ushort)hr;
  float hf = __uint_as_float(hr << 16);
  float lf = x - hf;
  unsigned ul = __float_as_uint(lf);
  l = (ushort)((ul + 0x7FFFu + ((ul >> 16) & 1u)) >> 16);
}

// ---- prep: w2 = W @ a_w[D:2D] ----
__global__ void prep_w2(const float* __restrict__ W, const float* __restrict__ a_w,
                        float* __restrict__ w2) {
  int i = threadIdx.x;  // 0..255
  float s = 0.f;
  for (int j = 0; j < DD; ++j) s = fmaf(W[i * DD + j], a_w[DD + j], s);
  w2[i] = s;
}

// ---- pre-split Wm_o into MFMA-fragment-ordered bf16 hi/lo ----
// frag element: b[j] = B[k][col], k = kc16*32 + (lane>>4)*8 + j, col = nf*16 + (lane&15)
// offset = (((kc16*16)+nf)*64 + lane)*8 + j
__global__ void bsplit_kernel(const float* __restrict__ Wm,
                              ushort* __restrict__ Bh, ushort* __restrict__ Bl) {
  int i = blockIdx.x * 256 + threadIdx.x;  // 0..131071
  int k = i >> 8, col = i & 255;
  ushort h, l;
  split1(Wm[i], h, l);
  int kc16 = k >> 5, kr = k & 31;
  int lane = ((kr >> 3) << 4) | (col & 15);
  int nf = col >> 4;
  int off = (((((kc16 << 4) + nf) << 6) + lane) << 3) + (kr & 7);
  Bh[off] = h;
  Bl[off] = l;
}

// ---- MFMA mapping GEMM: Yn = l2norm(relu(X@Wm+bm)); norms + s_dst fused ----
// block: 256 thr / 4 waves; tile 64 rows x 256 cols; wave w -> cols [w*64, w*64+64)
__global__ __launch_bounds__(256, 2) void map_gemm_mfma(
    const float* __restrict__ X, const ushort* __restrict__ Bh,
    const ushort* __restrict__ Bl, const float* __restrict__ bm,
    const float* __restrict__ w2, float* __restrict__ Yn,
    float* __restrict__ norms, float* __restrict__ sdst, int M) {
  __shared__ ushort Ah[4096];  // 64 rows x 64 k (bf16 hi), XOR-swizzled
  __shared__ ushort Al[4096];
  const int t = threadIdx.x;
  const int w = t >> 6;
  const int l = t & 63;
  const int c = l & 15;   // frag col / A-row-in-frag
  const int g = l >> 4;   // k-chunk group / C row-group
  const int row0 = blockIdx.x * 64;

  // A staging map: thread -> row t>>2, 16 consecutive k at (t&3)*16
  const int sr = t >> 2;
  const int skb = (t & 3) << 4;
  int gr = row0 + sr;
  if (gr >= M) gr = M - 1;
  const float* xrow = X + (size_t)gr * IN_DIM;

  f32x4_t acc[4][4];
#pragma unroll
  for (int m = 0; m < 4; ++m)
#pragma unroll
    for (int n = 0; n < 4; ++n) acc[m][n] = (f32x4_t){0.f, 0.f, 0.f, 0.f};

  float4 r0, r1, r2, r3;
  {
    const float4* p = reinterpret_cast<const float4*>(xrow + skb);
    r0 = p[0]; r1 = p[1]; r2 = p[2]; r3 = p[3];
  }

  const int sw = (sr & 7) << 3;
  const int i0 = ((sr << 6) + skb);

  for (int ks = 0; ks < 8; ++ks) {
    // convert staged regs -> bf16 hi/lo fragments
    short8_t h0, h1, l0, l1;
    {
      ushort hh, ll;
#define CV(F, V, J) { split1(F, hh, ll); V[J] = (short)hh; (&l0)[(&V - &h0)][J] = (short)ll; }
      // (macro trickery avoided -- explicit)
      split1(r0.x, hh, ll); h0[0] = (short)hh; l0[0] = (short)ll;
      split1(r0.y, hh, ll); h0[1] = (short)hh; l0[1] = (short)ll;
      split1(r0.z, hh, ll); h0[2] = (short)hh; l0[2] = (short)ll;
      split1(r0.w, hh, ll); h0[3] = (short)hh; l0[3] = (short)ll;
      split1(r1.x, hh, ll); h0[4] = (short)hh; l0[4] = (short)ll;
      split1(r1.y, hh, ll); h0[5] = (short)hh; l0[5] = (short)ll;
      split1(r1.z, hh, ll); h0[6] = (short)hh; l0[6] = (short)ll;
      split1(r1.w, hh, ll); h0[7] = (short)hh; l0[7] = (short)ll;
      split1(r2.x, hh, ll); h1[0] = (short)hh; l1[0] = (short)ll;
      split1(r2.y, hh, ll); h1[1] = (short)hh; l1[1] = (short)ll;
      split1(r2.z, hh, ll); h1[2] = (short)hh; l1[2] = (short)ll;
      split1(r2.w, hh, ll); h1[3] = (short)hh; l1[3] = (short)ll;
      split1(r3.x, hh, ll); h1[4] = (short)hh; l1[4] = (short)ll;
      split1(r3.y, hh, ll); h1[5] = (short)hh; l1[5] = (short)ll;
      split1(r3.z, hh, ll); h1[6] = (short)hh; l1[6] = (short)ll;
      split1(r3.w, hh, ll); h1[7] = (short)hh; l1[7] = (short)ll;
#undef CV
    }
    __syncthreads();  // all waves done reading previous A tile
    *reinterpret_cast<short8_t*>(&Ah[i0 ^ sw]) = h0;
    *reinterpret_cast<short8_t*>(&Ah[(i0 + 8) ^ sw]) = h1;
    *reinterpret_cast<short8_t*>(&Al[i0 ^ sw]) = l0;
    *reinterpret_cast<short8_t*>(&Al[(i0 + 8) ^ sw]) = l1;
    __syncthreads();

    if (ks < 7) {  // prefetch next A tile (overlaps MFMA phase)
      const float4* p = reinterpret_cast<const float4*>(xrow + ((ks + 1) << 6) + skb);
      r0 = p[0]; r1 = p[1]; r2 = p[2]; r3 = p[3];
    }

#pragma unroll
    for (int kc = 0; kc < 2; ++kc) {
      const int kc16 = (ks << 1) + kc;
      short8_t bh[4], bl[4];
#pragma unroll
      for (int n = 0; n < 4; ++n) {
        int boff = ((((kc16 << 4) + (w << 2) + n) << 6) + l) << 3;
        bh[n] = *reinterpret_cast<const short8_t*>(Bh + boff);
        bl[n] = *reinterpret_cast<const short8_t*>(Bl + boff);
      }
      short8_t ah[4], av[4];
#pragma unroll
      for (int m = 0; m < 4; ++m) {
        int r = (m << 4) + c;
        int idx = ((r << 6) + (kc << 5) + (g << 3)) ^ ((r & 7) << 3);
        ah[m] = *reinterpret_cast<const short8_t*>(&Ah[idx]);
        av[m] = *reinterpret_cast<const short8_t*>(&Al[idx]);
      }
#pragma unroll
      for (int m = 0; m < 4; ++m)
#pragma unroll
        for (int n = 0; n < 4; ++n) {
          acc[m][n] = __builtin_amdgcn_mfma_f32_16x16x32_bf16(ah[m], bh[n], acc[m][n], 0, 0, 0);
          acc[m][n] = __builtin_amdgcn_mfma_f32_16x16x32_bf16(ah[m], bl[n], acc[m][n], 0, 0, 0);
          acc[m][n] = __builtin_amdgcn_mfma_f32_16x16x32_bf16(av[m], bh[n], acc[m][n], 0, 0, 0);
        }
    }
  }

  // ---- epilogue: bias+relu, fused row-dot (s_dst) + row-norm, normalized store ----
  float bv[4], wv[4];
#pragma unroll
  for (int n = 0; n < 4; ++n) {
    bv[n] = bm[(w << 6) + (n << 4) + c];
    wv[n] = w2[(w << 6) + (n << 4) + c];
  }
#pragma unroll
  for (int m = 0; m < 4; ++m)
#pragma unroll
    for (int n = 0; n < 4; ++n)
#pragma unroll
      for (int q = 0; q < 4; ++q) {
        float v = acc[m][n][q] + bv[n];
        acc[m][n][q] = v > 0.f ? v : 0.f;
      }

  float* red = reinterpret_cast<float*>(Ah);  // overlay reduce space on A LDS
  float pss[4][4], pdt[4][4];
#pragma unroll
  for (int m = 0; m < 4; ++m)
#pragma unroll
    for (int q = 0; q < 4; ++q) {
      float ss = 0.f, dt = 0.f;
#pragma unroll
      for (int n = 0; n < 4; ++n) {
        float a = acc[m][n][q];
        ss = fmaf(a, a, ss);
        dt = fmaf(a, wv[n], dt);
      }
      for (int d = 8; d; d >>= 1) {
        ss += __shfl_down(ss, d, 16);
        dt += __shfl_down(dt, d, 16);
      }
      pss[m][q] = ss;
      pdt[m][q] = dt;
    }
  __syncthreads();  // all waves done with A LDS from main loop
#pragma unroll
  for (int m = 0; m < 4; ++m)
#pragma unroll
    for (int q = 0; q < 4; ++q)
      if (c == 0) {
        int rr = (m << 4) + (g << 2) + q;
        red[(w << 6) + rr] = pss[m][q];
        red[256 + (w << 6) + rr] = pdt[m][q];
      }
  __syncthreads();
  if (t < 64) {
    float ss = red[t] + red[64 + t] + red[128 + t] + red[192 + t];
    float dt = red[256 + t] + red[320 + t] + red[384 + t] + red[448 + t];
    float nr = sqrtf(ss);
    red[512 + t] = 1.f / fmaxf(nr, 1e-12f);
    int r = row0 + t;
    if (r < M) {
      norms[r] = nr;
      sdst[r] = dt;
    }
  }
  __syncthreads();
#pragma unroll
  for (int m = 0; m < 4; ++m)
#pragma unroll
    for (int q = 0; q < 4; ++q) {
      int rr = (m << 4) + (g << 2) + q;
      float sc = red[512 + rr];
      int r = row0 + rr;
      if (r < M) {
#pragma unroll
        for (int n = 0; n < 4; ++n)
          Yn[(size_t)r * DD + (w << 6) + (n << 4) + c] = acc[m][n][q] * sc;
      }
    }
}

// ---- CSR build ----
__global__ void hist_kernel(const int* __restrict__ src, int* __restrict__ deg, int E) {
  int i = blockIdx.x * blockDim.x + threadIdx.x;
  if (i < E) atomicAdd(&deg[src[i]], 1);
}

#define SCAN_T 1024
__global__ __launch_bounds__(SCAN_T) void scan_kernel(
    const int* __restrict__ deg, int* __restrict__ rowptr,
    int* __restrict__ cursor, int NP) {
  __shared__ int sums[SCAN_T];
  int t = threadIdx.x;
  int items = (NP + SCAN_T - 1) / SCAN_T;
  int beg = t * items;
  int end = beg + items; if (end > NP) end = NP; if (beg > NP) beg = NP;
  int local = 0;
  for (int i = beg; i < end; ++i) local += deg[i];
  sums[t] = local;
  __syncthreads();
  for (int off = 1; off < SCAN_T; off <<= 1) {
    int u = (t >= off) ? sums[t - off] : 0;
    __syncthreads();
    sums[t] += u;
    __syncthreads();
  }
  int run = sums[t] - local;
  for (int i = beg; i < end; ++i) {
    rowptr[i] = run;
    cursor[i] = run;
    run += deg[i];
  }
  if (t == SCAN_T - 1) rowptr[NP] = run;
}

__global__ void fill_kernel(const int* __restrict__ src, const int* __restrict__ dst,
                            int* __restrict__ cursor, int* __restrict__ ebuf, int E) {
  int i = blockIdx.x * blockDim.x + threadIdx.x;
  if (i < E) {
    int pos = atomicAdd(&cursor[src[i]], 1);
    ebuf[pos] = dst[i];
  }
}

// ---- per-segment softmax + weighted gather of NORMALIZED ho (x norms) + fused l2norm ----
__global__ void agg_kernel(const int* __restrict__ rowptr, const int* __restrict__ ebuf,
                           const float* __restrict__ s_dst, const float* __restrict__ norms,
                           const float* __restrict__ hon, float* __restrict__ agg, int NP) {
  int p = (int)(((long)blockIdx.x * blockDim.x + threadIdx.x) >> 6);
  int lane = threadIdx.x & 63;
  if (p >= NP) return;
  int beg = rowptr[p], end = rowptr[p + 1];
  float4 acc = {0.f, 0.f, 0.f, 0.f};
  if (beg < end) {
    float m = NEG_INF;
    for (int j0 = beg; j0 < end; j0 += 64) {
      int j = j0 + lane;
      float v = (j < end) ? s_dst[ebuf[j]] : NEG_INF;
      m = fmaxf(m, v);
    }
#pragma unroll
    for (int d = 32; d > 0; d >>= 1) m = fmaxf(m, __shfl_xor(m, d, 64));
    float denom = 0.f;
    for (int j0 = beg; j0 < end; j0 += 64) {
      int j = j0 + lane;
      denom += (j < end) ? __expf(s_dst[ebuf[j]] - m) : 0.f;
    }
#pragma unroll
    for (int d = 32; d > 0; d >>= 1) denom += __shfl_xor(denom, d, 64);
    float inv_denom = 1.f / denom;
    for (int j = beg; j < end; ++j) {
      int dd = ebuf[j];
      float wgt = __expf(s_dst[dd] - m) * inv_denom * norms[dd];
      float4 v = *reinterpret_cast<const float4*>(&hon[(size_t)dd * DD + lane * 4]);
      acc.x = fmaf(wgt, v.x, acc.x);
      acc.y = fmaf(wgt, v.y, acc.y);
      acc.z = fmaf(wgt, v.z, acc.z);
      acc.w = fmaf(wgt, v.w, acc.w);
    }
  }
  float ss = acc.x * acc.x + acc.y * acc.y + acc.z * acc.z + acc.w * acc.w;
#pragma unroll
  for (int d = 32; d > 0; d >>= 1) ss += __shfl_xor(ss, d, 64);
  float inv = 1.0f / fmaxf(sqrtf(ss), 1e-12f);
  float4 o = {acc.x * inv, acc.y * inv, acc.z * inv, acc.w * inv};
  *reinterpret_cast<float4*>(&agg[(size_t)p * DD + lane * 4]) = o;
}

extern "C" void kernel_launch(void* const* d_in, const int* in_sizes, int n_in,
                              void* d_out, int out_size, void* d_ws, size_t ws_size,
                              hipStream_t stream) {
  const float* feat_other = (const float*)d_in[1];
  const int* src = (const int*)d_in[2];
  const int* dst = (const int*)d_in[3];
  const float* Wm_o = (const float*)d_in[6];
  const float* bm_o = (const float*)d_in[7];
  const float* W = (const float*)d_in[8];
  const float* a_w = (const float*)d_in[10];

  const int NP = in_sizes[0] / IN_DIM;
  const int NO = in_sizes[1] / IN_DIM;
  const int E = in_sizes[2];

  float* out = (float*)d_out;
  float* agg_out = out;                      // [NP, DD] (normalized agg)
  float* ho_out = out + (size_t)NP * DD;     // [NO, DD] (normalized ho)

  // workspace layout (floats)
  float* ws = (float*)d_ws;
  float* s_dst = ws;                          // NO
  float* norms = s_dst + NO;                  // NO
  float* w2 = norms + NO;                     // 256
  int* deg = (int*)(w2 + 256);                // NP (memset 0)
  int* rowptr = deg + NP;                     // NP+1
  int* cursor = rowptr + NP + 1;              // NP
  int* ebuf = cursor + NP;                    // E
  size_t foff = (size_t)(2 * NO) + 256 + NP + (NP + 1) + NP + E;
  foff = (foff + 3) & ~(size_t)3;             // 16B align
  ushort* Bh = (ushort*)(ws + foff);          // 131072 ushorts
  ushort* Bl = Bh + (size_t)IN_DIM * DD;      // 131072 ushorts

  hipMemsetAsync(deg, 0, (size_t)NP * sizeof(int), stream);

  prep_w2<<<1, 256, 0, stream>>>(W, a_w, w2);
  bsplit_kernel<<<(IN_DIM * DD) / 256, 256, 0, stream>>>(Wm_o, Bh, Bl);

  map_gemm_mfma<<<(NO + 63) / 64, 256, 0, stream>>>(
      feat_other, Bh, Bl, bm_o, w2, ho_out, norms, s_dst, NO);

  hist_kernel<<<(E + 255) / 256, 256, 0, stream>>>(src, deg, E);
  scan_kernel<<<1, SCAN_T, 0, stream>>>(deg, rowptr, cursor, NP);
  fill_kernel<<<(E + 255) / 256, 256, 0, stream>>>(src, dst, cursor, ebuf, E);

  agg_kernel<<<(NP * 64 + 255) / 256, 256, 0, stream>>>(
      rowptr, ebuf, s_dst, norms, ho_out, agg_out, NP);
}

// Round 4
// 465.670 us; speedup vs baseline: 5.9262x; 1.2980x over previous
//
#include <hip/hip_runtime.h>
#include <math.h>

#define IN_DIM 512
#define DD 256
#define NEG_INF -3.402823466e+38f

typedef __attribute__((ext_vector_type(8))) short short8_t;
typedef __attribute__((ext_vector_type(4))) float f32x4_t;

// ---- RNE split: x ~= hi(bf16) + lo(bf16), err ~2^-18 rel ----
__device__ __forceinline__ void split1(float x, ushort& h, ushort& l) {
  unsigned u = __float_as_uint(x);
  unsigned hr = (u + 0x7FFFu + ((u >> 16) & 1u)) >> 16;
  h = (ushort)hr;
  float hf = __uint_as_float(hr << 16);
  float lf = x - hf;
  unsigned ul = __float_as_uint(lf);
  l = (ushort)((ul + 0x7FFFu + ((ul >> 16) & 1u)) >> 16);
}

// ---- prep: w2 = W @ a_w[D:2D] ----
__global__ void prep_w2(const float* __restrict__ W, const float* __restrict__ a_w,
                        float* __restrict__ w2) {
  int i = threadIdx.x;  // 0..255
  float s = 0.f;
  for (int j = 0; j < DD; ++j) s = fmaf(W[i * DD + j], a_w[DD + j], s);
  w2[i] = s;
}

// ---- pre-split Wm_o into MFMA-fragment-ordered bf16 hi/lo ----
__global__ void bsplit_kernel(const float* __restrict__ Wm,
                              ushort* __restrict__ Bh, ushort* __restrict__ Bl) {
  int i = blockIdx.x * 256 + threadIdx.x;  // 0..131071
  int k = i >> 8, col = i & 255;
  ushort h, l;
  split1(Wm[i], h, l);
  int kc16 = k >> 5, kr = k & 31;
  int lane = ((kr >> 3) << 4) | (col & 15);
  int nf = col >> 4;
  int off = (((((kc16 << 4) + nf) << 6) + lane) << 3) + (kr & 7);
  Bh[off] = h;
  Bl[off] = l;
}

// ---- MFMA mapping GEMM + fused epilogue: Yn = l2norm(relu(X@Wm+bm));
//      tvals = exp(h.w2), wnorm = tvals * ||h|| ----
__global__ __launch_bounds__(256, 2) void map_gemm_mfma(
    const float* __restrict__ X, const ushort* __restrict__ Bh,
    const ushort* __restrict__ Bl, const float* __restrict__ bm,
    const float* __restrict__ w2, float* __restrict__ Yn,
    float* __restrict__ tvals, float* __restrict__ wnorm, int M) {
  __shared__ ushort Ah[4096];  // 64 rows x 64 k (bf16 hi), XOR-swizzled
  __shared__ ushort Al[4096];
  const int t = threadIdx.x;
  const int w = t >> 6;
  const int l = t & 63;
  const int c = l & 15;
  const int g = l >> 4;
  const int row0 = blockIdx.x * 64;

  const int sr = t >> 2;
  const int skb = (t & 3) << 4;
  int gr = row0 + sr;
  if (gr >= M) gr = M - 1;
  const float* xrow = X + (size_t)gr * IN_DIM;

  f32x4_t acc[4][4];
#pragma unroll
  for (int m = 0; m < 4; ++m)
#pragma unroll
    for (int n = 0; n < 4; ++n) acc[m][n] = (f32x4_t){0.f, 0.f, 0.f, 0.f};

  float4 r0, r1, r2, r3;
  {
    const float4* p = reinterpret_cast<const float4*>(xrow + skb);
    r0 = p[0]; r1 = p[1]; r2 = p[2]; r3 = p[3];
  }

  const int sw = (sr & 7) << 3;
  const int i0 = ((sr << 6) + skb);
  const short8_t* bhb = reinterpret_cast<const short8_t*>(Bh);
  const short8_t* blb = reinterpret_cast<const short8_t*>(Bl);

  for (int ks = 0; ks < 8; ++ks) {
    short8_t h0, h1, l0, l1;
    {
      ushort hh, ll;
      split1(r0.x, hh, ll); h0[0] = (short)hh; l0[0] = (short)ll;
      split1(r0.y, hh, ll); h0[1] = (short)hh; l0[1] = (short)ll;
      split1(r0.z, hh, ll); h0[2] = (short)hh; l0[2] = (short)ll;
      split1(r0.w, hh, ll); h0[3] = (short)hh; l0[3] = (short)ll;
      split1(r1.x, hh, ll); h0[4] = (short)hh; l0[4] = (short)ll;
      split1(r1.y, hh, ll); h0[5] = (short)hh; l0[5] = (short)ll;
      split1(r1.z, hh, ll); h0[6] = (short)hh; l0[6] = (short)ll;
      split1(r1.w, hh, ll); h0[7] = (short)hh; l0[7] = (short)ll;
      split1(r2.x, hh, ll); h1[0] = (short)hh; l1[0] = (short)ll;
      split1(r2.y, hh, ll); h1[1] = (short)hh; l1[1] = (short)ll;
      split1(r2.z, hh, ll); h1[2] = (short)hh; l1[2] = (short)ll;
      split1(r2.w, hh, ll); h1[3] = (short)hh; l1[3] = (short)ll;
      split1(r3.x, hh, ll); h1[4] = (short)hh; l1[4] = (short)ll;
      split1(r3.y, hh, ll); h1[5] = (short)hh; l1[5] = (short)ll;
      split1(r3.z, hh, ll); h1[6] = (short)hh; l1[6] = (short)ll;
      split1(r3.w, hh, ll); h1[7] = (short)hh; l1[7] = (short)ll;
    }
    __syncthreads();
    *reinterpret_cast<short8_t*>(&Ah[i0 ^ sw]) = h0;
    *reinterpret_cast<short8_t*>(&Ah[(i0 + 8) ^ sw]) = h1;
    *reinterpret_cast<short8_t*>(&Al[i0 ^ sw]) = l0;
    *reinterpret_cast<short8_t*>(&Al[(i0 + 8) ^ sw]) = l1;
    __syncthreads();

    if (ks < 7) {  // prefetch next A tile (overlaps MFMA phase)
      const float4* p = reinterpret_cast<const float4*>(xrow + ((ks + 1) << 6) + skb);
      r0 = p[0]; r1 = p[1]; r2 = p[2]; r3 = p[3];
    }

#pragma unroll
    for (int kc = 0; kc < 2; ++kc) {
      const int kc16 = (ks << 1) + kc;
      short8_t ah[4], av[4];
#pragma unroll
      for (int m = 0; m < 4; ++m) {
        int r = (m << 4) + c;
        int idx = ((r << 6) + (kc << 5) + (g << 3)) ^ ((r & 7) << 3);
        ah[m] = *reinterpret_cast<const short8_t*>(&Ah[idx]);
        av[m] = *reinterpret_cast<const short8_t*>(&Al[idx]);
      }
      const int base = (((kc16 << 4) + (w << 2)) << 6) + l;
      short8_t bh = bhb[base], bl = blb[base];
#pragma unroll
      for (int n = 0; n < 4; ++n) {
        short8_t bhn = bh, bln = bl;
        if (n < 3) {  // prefetch next B column fragment
          bhn = bhb[base + ((n + 1) << 6)];
          bln = blb[base + ((n + 1) << 6)];
        }
#pragma unroll
        for (int m = 0; m < 4; ++m) {
          acc[m][n] = __builtin_amdgcn_mfma_f32_16x16x32_bf16(ah[m], bh, acc[m][n], 0, 0, 0);
          acc[m][n] = __builtin_amdgcn_mfma_f32_16x16x32_bf16(ah[m], bl, acc[m][n], 0, 0, 0);
          acc[m][n] = __builtin_amdgcn_mfma_f32_16x16x32_bf16(av[m], bh, acc[m][n], 0, 0, 0);
        }
        bh = bhn; bl = bln;
      }
    }
  }

  // ---- epilogue: bias+relu, fused row-dot + row-norm, exp, normalized store ----
  float bv[4], wv[4];
#pragma unroll
  for (int n = 0; n < 4; ++n) {
    bv[n] = bm[(w << 6) + (n << 4) + c];
    wv[n] = w2[(w << 6) + (n << 4) + c];
  }
#pragma unroll
  for (int m = 0; m < 4; ++m)
#pragma unroll
    for (int n = 0; n < 4; ++n)
#pragma unroll
      for (int q = 0; q < 4; ++q) {
        float v = acc[m][n][q] + bv[n];
        acc[m][n][q] = v > 0.f ? v : 0.f;
      }

  float* red = reinterpret_cast<float*>(Ah);
  float pss[4][4], pdt[4][4];
#pragma unroll
  for (int m = 0; m < 4; ++m)
#pragma unroll
    for (int q = 0; q < 4; ++q) {
      float ss = 0.f, dt = 0.f;
#pragma unroll
      for (int n = 0; n < 4; ++n) {
        float a = acc[m][n][q];
        ss = fmaf(a, a, ss);
        dt = fmaf(a, wv[n], dt);
      }
      for (int d = 8; d; d >>= 1) {
        ss += __shfl_down(ss, d, 16);
        dt += __shfl_down(dt, d, 16);
      }
      pss[m][q] = ss;
      pdt[m][q] = dt;
    }
  __syncthreads();
#pragma unroll
  for (int m = 0; m < 4; ++m)
#pragma unroll
    for (int q = 0; q < 4; ++q)
      if (c == 0) {
        int rr = (m << 4) + (g << 2) + q;
        red[(w << 6) + rr] = pss[m][q];
        red[256 + (w << 6) + rr] = pdt[m][q];
      }
  __syncthreads();
  if (t < 64) {
    float ss = red[t] + red[64 + t] + red[128 + t] + red[192 + t];
    float dt = red[256 + t] + red[320 + t] + red[384 + t] + red[448 + t];
    float nr = sqrtf(ss);
    red[512 + t] = 1.f / fmaxf(nr, 1e-12f);
    int r = row0 + t;
    if (r < M) {
      float tv = expf(dt);
      tvals[r] = tv;
      wnorm[r] = tv * nr;
    }
  }
  __syncthreads();
#pragma unroll
  for (int m = 0; m < 4; ++m)
#pragma unroll
    for (int q = 0; q < 4; ++q) {
      int rr = (m << 4) + (g << 2) + q;
      float sc = red[512 + rr];
      int r = row0 + rr;
      if (r < M) {
#pragma unroll
        for (int n = 0; n < 4; ++n)
          Yn[(size_t)r * DD + (w << 6) + (n << 4) + c] = acc[m][n][q] * sc;
      }
    }
}

// ---- CSR build ----
__global__ void hist_kernel(const int* __restrict__ src, int* __restrict__ deg, int E) {
  int i = blockIdx.x * blockDim.x + threadIdx.x;
  if (i < E) atomicAdd(&deg[src[i]], 1);
}

// hierarchical exclusive scan: 256 blocks x 256 thr x 2 items
__global__ __launch_bounds__(256) void scan_part(const int* __restrict__ deg,
                                                 int* __restrict__ bsum, int NP) {
  __shared__ int s[256];
  int t = threadIdx.x, b = blockIdx.x;
  int i0 = (b * 256 + t) * 2;
  int v0 = (i0 < NP) ? deg[i0] : 0;
  int v1 = (i0 + 1 < NP) ? deg[i0 + 1] : 0;
  s[t] = v0 + v1;
  __syncthreads();
  for (int off = 128; off; off >>= 1) {
    if (t < off) s[t] += s[t + off];
    __syncthreads();
  }
  if (t == 0) bsum[b] = s[0];
}

__global__ __launch_bounds__(256) void scan_top(int* __restrict__ bsum,
                                                int* __restrict__ rowptr_last) {
  __shared__ int s[256];
  int t = threadIdx.x;
  int v = bsum[t];
  s[t] = v;
  __syncthreads();
  for (int off = 1; off < 256; off <<= 1) {
    int u = (t >= off) ? s[t - off] : 0;
    __syncthreads();
    s[t] += u;
    __syncthreads();
  }
  bsum[t] = s[t] - v;  // exclusive
  if (t == 255) *rowptr_last = s[255];
}

__global__ __launch_bounds__(256) void scan_fin(const int* __restrict__ deg,
                                                const int* __restrict__ bsum,
                                                int* __restrict__ rowptr,
                                                int* __restrict__ cursor, int NP) {
  __shared__ int s[256];
  int t = threadIdx.x, b = blockIdx.x;
  int i0 = (b * 256 + t) * 2;
  int v0 = (i0 < NP) ? deg[i0] : 0;
  int v1 = (i0 + 1 < NP) ? deg[i0 + 1] : 0;
  int local = v0 + v1;
  s[t] = local;
  __syncthreads();
  for (int off = 1; off < 256; off <<= 1) {
    int u = (t >= off) ? s[t - off] : 0;
    __syncthreads();
    s[t] += u;
    __syncthreads();
  }
  int base = bsum[b] + s[t] - local;
  if (i0 < NP) { rowptr[i0] = base; cursor[i0] = base; }
  if (i0 + 1 < NP) { rowptr[i0 + 1] = base + v0; cursor[i0 + 1] = base + v0; }
}

__global__ void fill_kernel(const int* __restrict__ src, const int* __restrict__ dst,
                            int* __restrict__ cursor, int* __restrict__ ebuf, int E) {
  int i = blockIdx.x * blockDim.x + threadIdx.x;
  if (i < E) {
    int pos = atomicAdd(&cursor[src[i]], 1);
    ebuf[pos] = dst[i];
  }
}

// ---- per-segment: denom = sum t[dst]; agg = sum (wn[dst]/denom) * hon[dst]; l2norm ----
__global__ void agg_kernel(const int* __restrict__ rowptr, const int* __restrict__ ebuf,
                           const float* __restrict__ tvals, const float* __restrict__ wnorm,
                           const float* __restrict__ hon, float* __restrict__ agg, int NP) {
  int p = (int)(((long)blockIdx.x * blockDim.x + threadIdx.x) >> 6);
  int lane = threadIdx.x & 63;
  if (p >= NP) return;
  int beg = rowptr[p], end = rowptr[p + 1];
  float4 acc = {0.f, 0.f, 0.f, 0.f};
  if (beg < end) {
    // lane-parallel denom (no max shift: scores are O(0.1))
    float den = 0.f;
    for (int j = beg + lane; j < end; j += 64) den += tvals[ebuf[j]];
#pragma unroll
    for (int d = 32; d > 0; d >>= 1) den += __shfl_xor(den, d, 64);
    float inv = 1.f / den;
    // 1-deep pipelined weighted row gather
    int d0 = ebuf[beg];
    float wcur = wnorm[d0];
    float4 v = *reinterpret_cast<const float4*>(&hon[(size_t)d0 * DD + lane * 4]);
    for (int j = beg + 1; j <= end; ++j) {
      float4 vn = {0.f, 0.f, 0.f, 0.f};
      float wnext = 0.f;
      if (j < end) {
        int dn = ebuf[j];
        wnext = wnorm[dn];
        vn = *reinterpret_cast<const float4*>(&hon[(size_t)dn * DD + lane * 4]);
      }
      float wa = wcur * inv;
      acc.x = fmaf(wa, v.x, acc.x);
      acc.y = fmaf(wa, v.y, acc.y);
      acc.z = fmaf(wa, v.z, acc.z);
      acc.w = fmaf(wa, v.w, acc.w);
      v = vn; wcur = wnext;
    }
  }
  float ss = acc.x * acc.x + acc.y * acc.y + acc.z * acc.z + acc.w * acc.w;
#pragma unroll
  for (int d = 32; d > 0; d >>= 1) ss += __shfl_xor(ss, d, 64);
  float inv = 1.0f / fmaxf(sqrtf(ss), 1e-12f);
  float4 o = {acc.x * inv, acc.y * inv, acc.z * inv, acc.w * inv};
  *reinterpret_cast<float4*>(&agg[(size_t)p * DD + lane * 4]) = o;
}

extern "C" void kernel_launch(void* const* d_in, const int* in_sizes, int n_in,
                              void* d_out, int out_size, void* d_ws, size_t ws_size,
                              hipStream_t stream) {
  const float* feat_other = (const float*)d_in[1];
  const int* src = (const int*)d_in[2];
  const int* dst = (const int*)d_in[3];
  const float* Wm_o = (const float*)d_in[6];
  const float* bm_o = (const float*)d_in[7];
  const float* W = (const float*)d_in[8];
  const float* a_w = (const float*)d_in[10];

  const int NP = in_sizes[0] / IN_DIM;
  const int NO = in_sizes[1] / IN_DIM;
  const int E = in_sizes[2];

  float* out = (float*)d_out;
  float* agg_out = out;                      // [NP, DD] (normalized agg)
  float* ho_out = out + (size_t)NP * DD;     // [NO, DD] (normalized ho)

  // workspace layout (floats)
  float* ws = (float*)d_ws;
  float* tvals = ws;                          // NO
  float* wnorm = tvals + NO;                  // NO
  float* w2 = wnorm + NO;                     // 256
  int* deg = (int*)(w2 + 256);                // NP (memset 0)
  int* rowptr = deg + NP;                     // NP+1
  int* cursor = rowptr + NP + 1;              // NP
  int* bsum = cursor + NP;                    // 256
  int* ebuf = bsum + 256;                     // E
  size_t foff = (size_t)(2 * NO) + 256 + NP + (NP + 1) + NP + 256 + E;
  foff = (foff + 3) & ~(size_t)3;             // 16B align
  ushort* Bh = (ushort*)(ws + foff);          // 131072 ushorts
  ushort* Bl = Bh + (size_t)IN_DIM * DD;      // 131072 ushorts

  hipMemsetAsync(deg, 0, (size_t)NP * sizeof(int), stream);

  prep_w2<<<1, 256, 0, stream>>>(W, a_w, w2);
  bsplit_kernel<<<(IN_DIM * DD) / 256, 256, 0, stream>>>(Wm_o, Bh, Bl);

  map_gemm_mfma<<<(NO + 63) / 64, 256, 0, stream>>>(
      feat_other, Bh, Bl, bm_o, w2, ho_out, tvals, wnorm, NO);

  hist_kernel<<<(E + 255) / 256, 256, 0, stream>>>(src, deg, E);
  scan_part<<<256, 256, 0, stream>>>(deg, bsum, NP);
  scan_top<<<1, 256, 0, stream>>>(bsum, rowptr + NP);
  scan_fin<<<256, 256, 0, stream>>>(deg, bsum, rowptr, cursor, NP);
  fill_kernel<<<(E + 255) / 256, 256, 0, stream>>>(src, dst, cursor, ebuf, E);

  agg_kernel<<<(NP * 64 + 255) / 256, 256, 0, stream>>>(
      rowptr, ebuf, tvals, wnorm, ho_out, agg_out, NP);
}